// Round 27
// baseline (31.045 us; speedup 1.0000x reference)
//
#include <hip/hip_runtime.h>

// VanillaGNN via MFMA: B=262144 graphs, N=8 nodes, DIN=3, DH=32, DOUT=1.
// r26 base (30.6us) + two independent low-risk levers:
//  (a) TPB 8->16, grid 1024->512 = EXACTLY 2 blocks/CU in ONE pass
//      (no second prologue, no inter-pass tail). LDS ~54.4KB, 2/CU fits.
//  (b) L1 in ONE MFMA via full 12-slot kappa-packing: one 32x32x16 step has
//      16 k-slots; the 4 split products + 2 bias halves need 14:
//      A q=0: [W1hi0-2, b1hi, W1hi0-2, b1lo]  q=1: [W1lo0-2, W1lo0-2, 0,0]
//      B q=0: [yhi0-2, 1, ylo0-2, 1]          q=1: [yhi0-2, ylo0-2, 0,0]
//      Sum = (W1hi+W1lo)(yhi+ylo) + b1 — same products, MFMA-internal
//      reassociation only. L1 chain 2 MFMA -> 1; 12 -> 10 MFMA/tile.
// CANARIES: absmax ~1.2207e-4 (>2e-4 = slot-map bug); LDS ~54.5K (>=62K =
// spill -> revert to r26 and declare); FETCH ~12.3MB.
// Per pipeline (2/wave, ILP2): y = A@x (24 fma) -> L1: 1 packed MFMA ->
// relu/cvt -> GEMM1: 2 MFMA (C=zerov) -> cvt -> AGG: 2 MFMA (C=b2rv) ->
// Wout reduce + shfl tree. MFMAs p0/p1 interleaved. Barrier-free main loop.
// Verified layouts (gfx950 mfma_f32_32x32x16_bf16, rounds 3-26):
//   A: lane row=l&31, k=8*(l>>5)+j   B: col=l&31, same k
//   C/D: col=l&31, row=(reg&3)+8*(reg>>2)+4*(l>>5)
// pi(kk) = (kk&3)+8*(kk>>2)+4q.
// Precision ledger (measured-free): tlo, w2lo, a32lo, plo.
// Falsified levers: occupancy (r13-19), forced envelope (r17/18 spill),
// ILP>=3 (r24), MFMA-L0 (r23 spill), C-op init (r21 null), barriers (r25 ~2%).

typedef __bf16 bf16x8 __attribute__((ext_vector_type(8)));
typedef float  f32x16 __attribute__((ext_vector_type(16)));

#define GPT 32   // graphs per tile (4 waves x 2 pipelines x 4 graphs)
#define TPB 16   // tiles per block (B = 512 * TPB * GPT exactly)

__global__ __launch_bounds__(256, 2) void gnn_kernel(
    const float* __restrict__ x,       // [B,8,3]
    const int* __restrict__ ei,        // [2,32] int32
    const float* __restrict__ W1,      // [3,32]
    const float* __restrict__ b1,      // [32]
    const float* __restrict__ W2,      // [32,32]
    const float* __restrict__ b2,      // [32]
    const float* __restrict__ Wout,    // [32]
    const float* __restrict__ bout,    // [1]
    float* __restrict__ out,           // [B]
    int B)
{
    __shared__ float As[64];           // A[n][m] (n=dst)
    __shared__ float degs[8], dinvs[8];
    __shared__ float W1s[96], b1s[32], W2s[1024], b2s[32], Wouts[32];
    __shared__ float xs[TPB * GPT * 24];  // 16 tiles x [g][8][3] = 48KB

    const int tid = threadIdx.x;

    // ---- stage weights / x (all 16 tiles) / build A — prologue ----
    if (tid < 96) W1s[tid] = W1[tid];
    if (tid < 64) As[tid] = 0.0f;
    if (tid < 32) { b1s[tid] = b1[tid]; b2s[tid] = b2[tid]; Wouts[tid] = Wout[tid]; }
    if (tid < 8)  degs[tid] = 1.0f;
    for (int i = tid; i < 1024; i += 256) W2s[i] = W2[i];
    {   // x: 3072 float4 per block, contiguous; 12 per thread
        const float4* x4 = reinterpret_cast<const float4*>(x);
        long long base4 = (long long)blockIdx.x * (TPB * GPT * 6);
        float4* xs4 = reinterpret_cast<float4*>(xs);
        #pragma unroll
        for (int i = 0; i < 12; i++)
            xs4[tid + 256 * i] = x4[base4 + tid + 256 * i];
    }
    __syncthreads();
    if (tid < 32) { int d = ei[32 + tid]; atomicAdd(&degs[d], 1.0f); }
    __syncthreads();
    if (tid < 8) dinvs[tid] = 1.0f / sqrtf(degs[tid]);
    __syncthreads();
    if (tid < 32) {
        int s = ei[tid], d = ei[32 + tid];
        atomicAdd(&As[d * 8 + s], dinvs[s] * dinvs[d]);
    } else if (tid < 40) {
        int n = tid - 32;
        atomicAdd(&As[n * 8 + n], dinvs[n] * dinvs[n]);
    }
    __syncthreads();   // last barrier — loop below is barrier-free

    // ---- per-lane constants ----
    const int lane = tid & 63;
    const int wv   = tid >> 6;    // wave 0..3
    const int r    = lane & 31;
    const int q    = lane >> 5;   // k-half selector
    const int n8   = r & 7;       // node within graph
    const int gl   = r >> 3;      // graph within pipeline
    const int g0   = wv * 4 + gl;       // pipeline-0 graph
    const int g1   = 16 + wv * 4 + gl;  // pipeline-1 graph

    float arow[8];
    #pragma unroll
    for (int m = 0; m < 8; m++) arow[m] = As[n8 * 8 + m];

    // L1 single-MFMA A-frag (12-slot kappa-packing, see header)
    bf16x8 w1A;
    {
        __bf16 h[3], l[3];
        #pragma unroll
        for (int j = 0; j < 3; j++) {
            float v = W1s[j * 32 + r];
            h[j] = (__bf16)v;
            l[j] = (__bf16)(v - (float)h[j]);
        }
        float bv = b1s[r];
        __bf16 bh = (__bf16)bv;
        __bf16 bl = (__bf16)(bv - (float)bh);
        w1A[0] = q ? l[0] : h[0];
        w1A[1] = q ? l[1] : h[1];
        w1A[2] = q ? l[2] : h[2];
        w1A[3] = q ? l[0] : bh;
        w1A[4] = q ? l[1] : h[0];
        w1A[5] = q ? l[2] : h[1];
        w1A[6] = q ? (__bf16)0.0f : h[2];
        w1A[7] = q ? (__bf16)0.0f : bl;
    }

    // W2 B-frags in pi-order (hi only)
    bf16x8 w2hi[2];
    #pragma unroll
    for (int s = 0; s < 2; s++) {
        #pragma unroll
        for (int j = 0; j < 8; j++) {
            int kk = 8 * s + j;
            int hid = (kk & 3) + 8 * (kk >> 2) + 4 * q;
            w2hi[s][j] = (__bf16)W2s[hid * 32 + r];
        }
    }
    // A32T B-frags in pi-order (hi only)
    bf16x8 a32hi[2];
    #pragma unroll
    for (int s = 0; s < 2; s++) {
        #pragma unroll
        for (int j = 0; j < 8; j++) {
            int kk = 8 * s + j;
            float v = ((kk >> 2) == gl) ? arow[(kk & 3) + 4 * q] : 0.0f;
            a32hi[s][j] = (__bf16)v;
        }
    }
    // persistent C-operand vectors + epilogue wout
    f32x16 zerov, b2rv;
    float woutr[16];
    #pragma unroll
    for (int k = 0; k < 16; k++) {
        int hk = (k & 3) + 8 * (k >> 2) + 4 * q;
        zerov[k] = 0.0f;
        b2rv[k] = b2s[hk];
        woutr[k] = Wouts[hk];
    }
    const float boutv = bout[0];

    // ---- barrier-free compute loop over the 16 pre-staged tiles ----
    #pragma unroll 4
    for (int it = 0; it < TPB; it++) {
        const long long gbase = ((long long)blockIdx.x * TPB + it) * GPT;
        const float* xt = &xs[it * GPT * 24];

        // ---- y = A@x, both pipelines ----
        float y00 = 0.f, y01 = 0.f, y02 = 0.f;
        {
            float xv[24];
            #pragma unroll
            for (int i = 0; i < 6; i++) {
                float4 v = *reinterpret_cast<const float4*>(&xt[g0 * 24 + i * 4]);
                xv[4 * i] = v.x; xv[4 * i + 1] = v.y; xv[4 * i + 2] = v.z; xv[4 * i + 3] = v.w;
            }
            #pragma unroll
            for (int m = 0; m < 8; m++) {
                y00 = fmaf(arow[m], xv[m * 3 + 0], y00);
                y01 = fmaf(arow[m], xv[m * 3 + 1], y01);
                y02 = fmaf(arow[m], xv[m * 3 + 2], y02);
            }
        }
        float y10 = 0.f, y11 = 0.f, y12 = 0.f;
        {
            float xv[24];
            #pragma unroll
            for (int i = 0; i < 6; i++) {
                float4 v = *reinterpret_cast<const float4*>(&xt[g1 * 24 + i * 4]);
                xv[4 * i] = v.x; xv[4 * i + 1] = v.y; xv[4 * i + 2] = v.z; xv[4 * i + 3] = v.w;
            }
            #pragma unroll
            for (int m = 0; m < 8; m++) {
                y10 = fmaf(arow[m], xv[m * 3 + 0], y10);
                y11 = fmaf(arow[m], xv[m * 3 + 1], y11);
                y12 = fmaf(arow[m], xv[m * 3 + 2], y12);
            }
        }

        // ---- yB, 12-slot packing (see header), both pipelines ----
        bf16x8 yB0, yB1;
        {
            __bf16 h0 = (__bf16)y00, h1 = (__bf16)y01, h2 = (__bf16)y02;
            __bf16 l0 = (__bf16)(y00 - (float)h0);
            __bf16 l1 = (__bf16)(y01 - (float)h1);
            __bf16 l2 = (__bf16)(y02 - (float)h2);
            yB0[0] = h0; yB0[1] = h1; yB0[2] = h2;
            yB0[3] = q ? l0 : (__bf16)1.0f;
            yB0[4] = q ? l1 : l0;
            yB0[5] = q ? l2 : l1;
            yB0[6] = q ? (__bf16)0.0f : l2;
            yB0[7] = q ? (__bf16)0.0f : (__bf16)1.0f;
            __bf16 m0 = (__bf16)y10, m1 = (__bf16)y11, m2 = (__bf16)y12;
            __bf16 n0 = (__bf16)(y10 - (float)m0);
            __bf16 n1 = (__bf16)(y11 - (float)m1);
            __bf16 n2 = (__bf16)(y12 - (float)m2);
            yB1[0] = m0; yB1[1] = m1; yB1[2] = m2;
            yB1[3] = q ? n0 : (__bf16)1.0f;
            yB1[4] = q ? n1 : n0;
            yB1[5] = q ? n2 : n1;
            yB1[6] = q ? (__bf16)0.0f : n2;
            yB1[7] = q ? (__bf16)0.0f : (__bf16)1.0f;
        }

        // ---- L1: ONE packed MFMA per pipeline; C = zerov ----
        f32x16 vacc0, vacc1;
        vacc0 = __builtin_amdgcn_mfma_f32_32x32x16_bf16(w1A, yB0, zerov, 0, 0, 0);
        vacc1 = __builtin_amdgcn_mfma_f32_32x32x16_bf16(w1A, yB1, zerov, 0, 0, 0);

        // ---- relu -> h1, hi-only A-frags ----
        bf16x8 phi0[2], phi1[2];
        #pragma unroll
        for (int s = 0; s < 2; s++) {
            #pragma unroll
            for (int j = 0; j < 8; j++) {
                phi0[s][j] = (__bf16)fmaxf(vacc0[8 * s + j], 0.0f);
                phi1[s][j] = (__bf16)fmaxf(vacc1[8 * s + j], 0.0f);
            }
        }

        // ---- GEMM1 MFMAs, interleaved; C = zerov ----
        vacc0 = __builtin_amdgcn_mfma_f32_32x32x16_bf16(phi0[0], w2hi[0], zerov, 0, 0, 0);
        vacc1 = __builtin_amdgcn_mfma_f32_32x32x16_bf16(phi1[0], w2hi[0], zerov, 0, 0, 0);
        vacc0 = __builtin_amdgcn_mfma_f32_32x32x16_bf16(phi0[1], w2hi[1], vacc0, 0, 0, 0);
        vacc1 = __builtin_amdgcn_mfma_f32_32x32x16_bf16(phi1[1], w2hi[1], vacc1, 0, 0, 0);

        // ---- t^T A-frags: hi-only DIRECT conversion ----
        bf16x8 thi0[2], thi1[2];
        #pragma unroll
        for (int s = 0; s < 2; s++) {
            #pragma unroll
            for (int j = 0; j < 8; j++) {
                thi0[s][j] = (__bf16)vacc0[8 * s + j];
                thi1[s][j] = (__bf16)vacc1[8 * s + j];
            }
        }

        // ---- AGG MFMAs, interleaved; C = b2rv ----
        vacc0 = __builtin_amdgcn_mfma_f32_32x32x16_bf16(thi0[0], a32hi[0], b2rv, 0, 0, 0);
        vacc1 = __builtin_amdgcn_mfma_f32_32x32x16_bf16(thi1[0], a32hi[0], b2rv, 0, 0, 0);
        vacc0 = __builtin_amdgcn_mfma_f32_32x32x16_bf16(thi0[1], a32hi[1], vacc0, 0, 0, 0);
        vacc1 = __builtin_amdgcn_mfma_f32_32x32x16_bf16(thi1[1], a32hi[1], vacc1, 0, 0, 0);

        // ---- epilogues, interleaved (independent shfl chains) ----
        float ss0 = 0.0f, ss1 = 0.0f;
        #pragma unroll
        for (int k = 0; k < 16; k++) {
            ss0 = fmaf(fmaxf(vacc0[k], 0.0f), woutr[k], ss0);
            ss1 = fmaf(fmaxf(vacc1[k], 0.0f), woutr[k], ss1);
        }
        ss0 += __shfl_xor(ss0, 32, 64);
        ss1 += __shfl_xor(ss1, 32, 64);
        float o0 = fmaxf(ss0 + boutv, 0.0f);
        float o1 = fmaxf(ss1 + boutv, 0.0f);
        o0 += __shfl_xor(o0, 1, 64);  o1 += __shfl_xor(o1, 1, 64);
        o0 += __shfl_xor(o0, 2, 64);  o1 += __shfl_xor(o1, 2, 64);
        o0 += __shfl_xor(o0, 4, 64);  o1 += __shfl_xor(o1, 4, 64);
        if (q == 0 && n8 == 0) {
            long long gg0 = gbase + g0;
            if (gg0 < (long long)B) out[gg0] = o0 * 0.125f;
            long long gg1 = gbase + g1;
            if (gg1 < (long long)B) out[gg1] = o1 * 0.125f;
        }
    }
}

extern "C" void kernel_launch(void* const* d_in, const int* in_sizes, int n_in,
                              void* d_out, int out_size, void* d_ws, size_t ws_size,
                              hipStream_t stream) {
    const float* x    = (const float*)d_in[0];
    const int*   ei   = (const int*)d_in[1];
    const float* W1   = (const float*)d_in[2];
    const float* b1   = (const float*)d_in[3];
    const float* W2   = (const float*)d_in[4];
    const float* b2   = (const float*)d_in[5];
    const float* Wout = (const float*)d_in[6];
    const float* bout = (const float*)d_in[7];
    float* out = (float*)d_out;
    (void)d_ws; (void)ws_size; (void)out_size; (void)n_in;

    const int B = in_sizes[0] / 24;            // 262144 = 512 * TPB * GPT exactly
    const int grid = B / (TPB * GPT);          // 512 blocks, 16 tiles each
    gnn_kernel<<<grid, 256, 0, stream>>>(x, ei, W1, b1, W2, b2, Wout, bout, out, B);
}

// Round 28
// 30.051 us; speedup vs baseline: 1.0331x; 1.0331x over previous
//
#include <hip/hip_runtime.h>

// VanillaGNN via MFMA: B=262144 graphs, N=8 nodes, DIN=3, DH=32, DOUT=1.
// r26 base (30.6us: TPB=8, grid=1024, barrier-free loop) + ONLY the r27-
// verified single-MFMA L1 (12-slot kappa-packing; absmax was bit-identical).
// r27's regression is attributed to TPB=16/grid=512 (zero-slack dispatch
// imbalance + longer serial staging) — decoupled A/B this round.
//   L1 packing: A q=0: [W1hi0-2, b1hi, W1hi0-2, b1lo] q=1: [W1lo0-2, W1lo0-2,0,0]
//               B q=0: [yhi0-2, 1, ylo0-2, 1]         q=1: [yhi0-2, ylo0-2, 0,0]
//   Sum = (W1hi+W1lo)(yhi+ylo) + b1. L1 = 1 MFMA; 10 MFMA/tile total.
// CANARIES: absmax exactly 1.2207e-4; LDS 30208 (+8KB = spill -> revert);
// FETCH ~12.3MB. If dur > 30.8: revert to r26 verbatim next round + declare.
// Per pipeline (2/wave, ILP2): y = A@x (24 fma) -> L1: 1 packed MFMA ->
// relu/cvt -> GEMM1: 2 MFMA (C=zerov) -> cvt -> AGG: 2 MFMA (C=b2rv) ->
// Wout reduce + shfl tree. MFMAs p0/p1 interleaved. Barrier-free main loop.
// Verified layouts (gfx950 mfma_f32_32x32x16_bf16, rounds 3-27):
//   A: lane row=l&31, k=8*(l>>5)+j   B: col=l&31, same k
//   C/D: col=l&31, row=(reg&3)+8*(reg>>2)+4*(l>>5)
// pi(kk) = (kk&3)+8*(kk>>2)+4q.
// Precision ledger (measured-free): tlo, w2lo, a32lo, plo; L1-pack exact.
// Falsified levers: occupancy (r13-19), forced envelope (r17/18), ILP>=3
// (r24), MFMA-L0 (r23), C-op init (r21 null), TPB=16 (r27).

typedef __bf16 bf16x8 __attribute__((ext_vector_type(8)));
typedef float  f32x16 __attribute__((ext_vector_type(16)));

#define GPT 32  // graphs per tile (4 waves x 2 pipelines x 4 graphs)
#define TPB 8   // tiles per block (B = 1024 * TPB * GPT exactly)

__global__ __launch_bounds__(256, 2) void gnn_kernel(
    const float* __restrict__ x,       // [B,8,3]
    const int* __restrict__ ei,        // [2,32] int32
    const float* __restrict__ W1,      // [3,32]
    const float* __restrict__ b1,      // [32]
    const float* __restrict__ W2,      // [32,32]
    const float* __restrict__ b2,      // [32]
    const float* __restrict__ Wout,    // [32]
    const float* __restrict__ bout,    // [1]
    float* __restrict__ out,           // [B]
    int B)
{
    __shared__ float As[64];           // A[n][m] (n=dst)
    __shared__ float degs[8], dinvs[8];
    __shared__ float W1s[96], b1s[32], W2s[1024], b2s[32], Wouts[32];
    __shared__ float xs[TPB * GPT * 24];  // 8 tiles x [g][8][3] = 24KB

    const int tid = threadIdx.x;

    // ---- stage weights / x (all 8 tiles) / build A — prologue ----
    if (tid < 96) W1s[tid] = W1[tid];
    if (tid < 64) As[tid] = 0.0f;
    if (tid < 32) { b1s[tid] = b1[tid]; b2s[tid] = b2[tid]; Wouts[tid] = Wout[tid]; }
    if (tid < 8)  degs[tid] = 1.0f;
    for (int i = tid; i < 1024; i += 256) W2s[i] = W2[i];
    {   // x: 1536 float4 per block, contiguous; 6 per thread
        const float4* x4 = reinterpret_cast<const float4*>(x);
        long long base4 = (long long)blockIdx.x * (TPB * GPT * 6);
        float4* xs4 = reinterpret_cast<float4*>(xs);
        #pragma unroll
        for (int i = 0; i < 6; i++)
            xs4[tid + 256 * i] = x4[base4 + tid + 256 * i];
    }
    __syncthreads();
    if (tid < 32) { int d = ei[32 + tid]; atomicAdd(&degs[d], 1.0f); }
    __syncthreads();
    if (tid < 8) dinvs[tid] = 1.0f / sqrtf(degs[tid]);
    __syncthreads();
    if (tid < 32) {
        int s = ei[tid], d = ei[32 + tid];
        atomicAdd(&As[d * 8 + s], dinvs[s] * dinvs[d]);
    } else if (tid < 40) {
        int n = tid - 32;
        atomicAdd(&As[n * 8 + n], dinvs[n] * dinvs[n]);
    }
    __syncthreads();   // last barrier — loop below is barrier-free

    // ---- per-lane constants ----
    const int lane = tid & 63;
    const int wv   = tid >> 6;    // wave 0..3
    const int r    = lane & 31;
    const int q    = lane >> 5;   // k-half selector
    const int n8   = r & 7;       // node within graph
    const int gl   = r >> 3;      // graph within pipeline
    const int g0   = wv * 4 + gl;       // pipeline-0 graph
    const int g1   = 16 + wv * 4 + gl;  // pipeline-1 graph

    float arow[8];
    #pragma unroll
    for (int m = 0; m < 8; m++) arow[m] = As[n8 * 8 + m];

    // L1 single-MFMA A-frag (12-slot kappa-packing, see header)
    bf16x8 w1A;
    {
        __bf16 h[3], l[3];
        #pragma unroll
        for (int j = 0; j < 3; j++) {
            float v = W1s[j * 32 + r];
            h[j] = (__bf16)v;
            l[j] = (__bf16)(v - (float)h[j]);
        }
        float bv = b1s[r];
        __bf16 bh = (__bf16)bv;
        __bf16 bl = (__bf16)(bv - (float)bh);
        w1A[0] = q ? l[0] : h[0];
        w1A[1] = q ? l[1] : h[1];
        w1A[2] = q ? l[2] : h[2];
        w1A[3] = q ? l[0] : bh;
        w1A[4] = q ? l[1] : h[0];
        w1A[5] = q ? l[2] : h[1];
        w1A[6] = q ? (__bf16)0.0f : h[2];
        w1A[7] = q ? (__bf16)0.0f : bl;
    }

    // W2 B-frags in pi-order (hi only)
    bf16x8 w2hi[2];
    #pragma unroll
    for (int s = 0; s < 2; s++) {
        #pragma unroll
        for (int j = 0; j < 8; j++) {
            int kk = 8 * s + j;
            int hid = (kk & 3) + 8 * (kk >> 2) + 4 * q;
            w2hi[s][j] = (__bf16)W2s[hid * 32 + r];
        }
    }
    // A32T B-frags in pi-order (hi only)
    bf16x8 a32hi[2];
    #pragma unroll
    for (int s = 0; s < 2; s++) {
        #pragma unroll
        for (int j = 0; j < 8; j++) {
            int kk = 8 * s + j;
            float v = ((kk >> 2) == gl) ? arow[(kk & 3) + 4 * q] : 0.0f;
            a32hi[s][j] = (__bf16)v;
        }
    }
    // persistent C-operand vectors + epilogue wout
    f32x16 zerov, b2rv;
    float woutr[16];
    #pragma unroll
    for (int k = 0; k < 16; k++) {
        int hk = (k & 3) + 8 * (k >> 2) + 4 * q;
        zerov[k] = 0.0f;
        b2rv[k] = b2s[hk];
        woutr[k] = Wouts[hk];
    }
    const float boutv = bout[0];

    // ---- barrier-free compute loop over the 8 pre-staged tiles ----
    #pragma unroll 4
    for (int it = 0; it < TPB; it++) {
        const long long gbase = ((long long)blockIdx.x * TPB + it) * GPT;
        const float* xt = &xs[it * GPT * 24];

        // ---- y = A@x, both pipelines ----
        float y00 = 0.f, y01 = 0.f, y02 = 0.f;
        {
            float xv[24];
            #pragma unroll
            for (int i = 0; i < 6; i++) {
                float4 v = *reinterpret_cast<const float4*>(&xt[g0 * 24 + i * 4]);
                xv[4 * i] = v.x; xv[4 * i + 1] = v.y; xv[4 * i + 2] = v.z; xv[4 * i + 3] = v.w;
            }
            #pragma unroll
            for (int m = 0; m < 8; m++) {
                y00 = fmaf(arow[m], xv[m * 3 + 0], y00);
                y01 = fmaf(arow[m], xv[m * 3 + 1], y01);
                y02 = fmaf(arow[m], xv[m * 3 + 2], y02);
            }
        }
        float y10 = 0.f, y11 = 0.f, y12 = 0.f;
        {
            float xv[24];
            #pragma unroll
            for (int i = 0; i < 6; i++) {
                float4 v = *reinterpret_cast<const float4*>(&xt[g1 * 24 + i * 4]);
                xv[4 * i] = v.x; xv[4 * i + 1] = v.y; xv[4 * i + 2] = v.z; xv[4 * i + 3] = v.w;
            }
            #pragma unroll
            for (int m = 0; m < 8; m++) {
                y10 = fmaf(arow[m], xv[m * 3 + 0], y10);
                y11 = fmaf(arow[m], xv[m * 3 + 1], y11);
                y12 = fmaf(arow[m], xv[m * 3 + 2], y12);
            }
        }

        // ---- yB, 12-slot packing (see header), both pipelines ----
        bf16x8 yB0, yB1;
        {
            __bf16 h0 = (__bf16)y00, h1 = (__bf16)y01, h2 = (__bf16)y02;
            __bf16 l0 = (__bf16)(y00 - (float)h0);
            __bf16 l1 = (__bf16)(y01 - (float)h1);
            __bf16 l2 = (__bf16)(y02 - (float)h2);
            yB0[0] = h0; yB0[1] = h1; yB0[2] = h2;
            yB0[3] = q ? l0 : (__bf16)1.0f;
            yB0[4] = q ? l1 : l0;
            yB0[5] = q ? l2 : l1;
            yB0[6] = q ? (__bf16)0.0f : l2;
            yB0[7] = q ? (__bf16)0.0f : (__bf16)1.0f;
            __bf16 m0 = (__bf16)y10, m1 = (__bf16)y11, m2 = (__bf16)y12;
            __bf16 n0 = (__bf16)(y10 - (float)m0);
            __bf16 n1 = (__bf16)(y11 - (float)m1);
            __bf16 n2 = (__bf16)(y12 - (float)m2);
            yB1[0] = m0; yB1[1] = m1; yB1[2] = m2;
            yB1[3] = q ? n0 : (__bf16)1.0f;
            yB1[4] = q ? n1 : n0;
            yB1[5] = q ? n2 : n1;
            yB1[6] = q ? (__bf16)0.0f : n2;
            yB1[7] = q ? (__bf16)0.0f : (__bf16)1.0f;
        }

        // ---- L1: ONE packed MFMA per pipeline; C = zerov ----
        f32x16 vacc0, vacc1;
        vacc0 = __builtin_amdgcn_mfma_f32_32x32x16_bf16(w1A, yB0, zerov, 0, 0, 0);
        vacc1 = __builtin_amdgcn_mfma_f32_32x32x16_bf16(w1A, yB1, zerov, 0, 0, 0);

        // ---- relu -> h1, hi-only A-frags ----
        bf16x8 phi0[2], phi1[2];
        #pragma unroll
        for (int s = 0; s < 2; s++) {
            #pragma unroll
            for (int j = 0; j < 8; j++) {
                phi0[s][j] = (__bf16)fmaxf(vacc0[8 * s + j], 0.0f);
                phi1[s][j] = (__bf16)fmaxf(vacc1[8 * s + j], 0.0f);
            }
        }

        // ---- GEMM1 MFMAs, interleaved; C = zerov ----
        vacc0 = __builtin_amdgcn_mfma_f32_32x32x16_bf16(phi0[0], w2hi[0], zerov, 0, 0, 0);
        vacc1 = __builtin_amdgcn_mfma_f32_32x32x16_bf16(phi1[0], w2hi[0], zerov, 0, 0, 0);
        vacc0 = __builtin_amdgcn_mfma_f32_32x32x16_bf16(phi0[1], w2hi[1], vacc0, 0, 0, 0);
        vacc1 = __builtin_amdgcn_mfma_f32_32x32x16_bf16(phi1[1], w2hi[1], vacc1, 0, 0, 0);

        // ---- t^T A-frags: hi-only DIRECT conversion ----
        bf16x8 thi0[2], thi1[2];
        #pragma unroll
        for (int s = 0; s < 2; s++) {
            #pragma unroll
            for (int j = 0; j < 8; j++) {
                thi0[s][j] = (__bf16)vacc0[8 * s + j];
                thi1[s][j] = (__bf16)vacc1[8 * s + j];
            }
        }

        // ---- AGG MFMAs, interleaved; C = b2rv ----
        vacc0 = __builtin_amdgcn_mfma_f32_32x32x16_bf16(thi0[0], a32hi[0], b2rv, 0, 0, 0);
        vacc1 = __builtin_amdgcn_mfma_f32_32x32x16_bf16(thi1[0], a32hi[0], b2rv, 0, 0, 0);
        vacc0 = __builtin_amdgcn_mfma_f32_32x32x16_bf16(thi0[1], a32hi[1], vacc0, 0, 0, 0);
        vacc1 = __builtin_amdgcn_mfma_f32_32x32x16_bf16(thi1[1], a32hi[1], vacc1, 0, 0, 0);

        // ---- epilogues, interleaved (independent shfl chains) ----
        float ss0 = 0.0f, ss1 = 0.0f;
        #pragma unroll
        for (int k = 0; k < 16; k++) {
            ss0 = fmaf(fmaxf(vacc0[k], 0.0f), woutr[k], ss0);
            ss1 = fmaf(fmaxf(vacc1[k], 0.0f), woutr[k], ss1);
        }
        ss0 += __shfl_xor(ss0, 32, 64);
        ss1 += __shfl_xor(ss1, 32, 64);
        float o0 = fmaxf(ss0 + boutv, 0.0f);
        float o1 = fmaxf(ss1 + boutv, 0.0f);
        o0 += __shfl_xor(o0, 1, 64);  o1 += __shfl_xor(o1, 1, 64);
        o0 += __shfl_xor(o0, 2, 64);  o1 += __shfl_xor(o1, 2, 64);
        o0 += __shfl_xor(o0, 4, 64);  o1 += __shfl_xor(o1, 4, 64);
        if (q == 0 && n8 == 0) {
            long long gg0 = gbase + g0;
            if (gg0 < (long long)B) out[gg0] = o0 * 0.125f;
            long long gg1 = gbase + g1;
            if (gg1 < (long long)B) out[gg1] = o1 * 0.125f;
        }
    }
}

extern "C" void kernel_launch(void* const* d_in, const int* in_sizes, int n_in,
                              void* d_out, int out_size, void* d_ws, size_t ws_size,
                              hipStream_t stream) {
    const float* x    = (const float*)d_in[0];
    const int*   ei   = (const int*)d_in[1];
    const float* W1   = (const float*)d_in[2];
    const float* b1   = (const float*)d_in[3];
    const float* W2   = (const float*)d_in[4];
    const float* b2   = (const float*)d_in[5];
    const float* Wout = (const float*)d_in[6];
    const float* bout = (const float*)d_in[7];
    float* out = (float*)d_out;
    (void)d_ws; (void)ws_size; (void)out_size; (void)n_in;

    const int B = in_sizes[0] / 24;            // 262144 = 1024 * TPB * GPT exactly
    const int grid = B / (TPB * GPT);          // 1024 blocks, 8 tiles each
    gnn_kernel<<<grid, 256, 0, stream>>>(x, ei, W1, b1, W2, b2, Wout, bout, out, B);
}

// Round 29
// 29.647 us; speedup vs baseline: 1.0471x; 1.0136x over previous
//
#include <hip/hip_runtime.h>

// VanillaGNN via MFMA: B=262144 graphs, N=8 nodes, DIN=3, DH=32, DOUT=1.
// r28 base (30.05us) + FINAL register-bin test: strip 48 luxury persistents.
//  (1) zerov removed -> explicit 0-init (r21 A/B: init movs are FREE)
//  (2) b2rv/woutr removed -> epilogue broadcast-float4 LDS reads (r12's
//      "conflicts" were PROVEN spill artifacts in r17/r18; broadcast reads
//      are 2-addr/wave = free per m136)
//  (3) AGG C = explicit 0-init; b2 added in epilogue (f32 add, exact).
// Leanest live set possible (~52 VGPR + 32 acc ~ 84 total). DECISIVE
// READOUT: OccupancyPercent. 25->37-50% = bin flipped, dur 24-27us.
// Stays 25% = 128-bin structurally unreachable -> revert r28 + declare.
// CANARIES: absmax exactly 1.2207e-4; LDS 30208 (+8KB = spill); FETCH ~12.3MB.
// Per pipeline (2/wave, ILP2): y = A@x (24 fma) -> L1: 1 packed MFMA ->
// relu/cvt -> GEMM1: 2 MFMA -> cvt -> AGG: 2 MFMA -> epilogue +b2/relu/wout
// from LDS + shfl tree. MFMAs p0/p1 interleaved. Barrier-free main loop.
// Verified layouts (gfx950 mfma_f32_32x32x16_bf16, rounds 3-28):
//   A: lane row=l&31, k=8*(l>>5)+j   B: col=l&31, same k
//   C/D: col=l&31, row=(reg&3)+8*(reg>>2)+4*(l>>5)
// L1 packing: A q=0:[W1hi0-2,b1hi,W1hi0-2,b1lo] q=1:[W1lo0-2,W1lo0-2,0,0]
//             B q=0:[yhi0-2,1,ylo0-2,1]         q=1:[yhi0-2,ylo0-2,0,0]
// Precision ledger (measured-free): tlo, w2lo, a32lo, plo; L1-pack exact.

typedef __bf16 bf16x8 __attribute__((ext_vector_type(8)));
typedef float  f32x16 __attribute__((ext_vector_type(16)));

#define GPT 32  // graphs per tile (4 waves x 2 pipelines x 4 graphs)
#define TPB 8   // tiles per block (B = 1024 * TPB * GPT exactly)

__global__ __launch_bounds__(256, 2) void gnn_kernel(
    const float* __restrict__ x,       // [B,8,3]
    const int* __restrict__ ei,        // [2,32] int32
    const float* __restrict__ W1,      // [3,32]
    const float* __restrict__ b1,      // [32]
    const float* __restrict__ W2,      // [32,32]
    const float* __restrict__ b2,      // [32]
    const float* __restrict__ Wout,    // [32]
    const float* __restrict__ bout,    // [1]
    float* __restrict__ out,           // [B]
    int B)
{
    __shared__ float As[64];           // A[n][m] (n=dst)
    __shared__ float degs[8], dinvs[8];
    __shared__ float W1s[96], b1s[32], W2s[1024], b2s[32], Wouts[32];
    __shared__ float xs[TPB * GPT * 24];  // 8 tiles x [g][8][3] = 24KB

    const int tid = threadIdx.x;

    // ---- stage weights / x (all 8 tiles) / build A — prologue ----
    if (tid < 96) W1s[tid] = W1[tid];
    if (tid < 64) As[tid] = 0.0f;
    if (tid < 32) { b1s[tid] = b1[tid]; b2s[tid] = b2[tid]; Wouts[tid] = Wout[tid]; }
    if (tid < 8)  degs[tid] = 1.0f;
    for (int i = tid; i < 1024; i += 256) W2s[i] = W2[i];
    {   // x: 1536 float4 per block, contiguous; 6 per thread
        const float4* x4 = reinterpret_cast<const float4*>(x);
        long long base4 = (long long)blockIdx.x * (TPB * GPT * 6);
        float4* xs4 = reinterpret_cast<float4*>(xs);
        #pragma unroll
        for (int i = 0; i < 6; i++)
            xs4[tid + 256 * i] = x4[base4 + tid + 256 * i];
    }
    __syncthreads();
    if (tid < 32) { int d = ei[32 + tid]; atomicAdd(&degs[d], 1.0f); }
    __syncthreads();
    if (tid < 8) dinvs[tid] = 1.0f / sqrtf(degs[tid]);
    __syncthreads();
    if (tid < 32) {
        int s = ei[tid], d = ei[32 + tid];
        atomicAdd(&As[d * 8 + s], dinvs[s] * dinvs[d]);
    } else if (tid < 40) {
        int n = tid - 32;
        atomicAdd(&As[n * 8 + n], dinvs[n] * dinvs[n]);
    }
    __syncthreads();   // last barrier — loop below is barrier-free

    // ---- per-lane constants ----
    const int lane = tid & 63;
    const int wv   = tid >> 6;    // wave 0..3
    const int r    = lane & 31;
    const int q    = lane >> 5;   // k-half selector
    const int n8   = r & 7;       // node within graph
    const int gl   = r >> 3;      // graph within pipeline
    const int g0   = wv * 4 + gl;       // pipeline-0 graph
    const int g1   = 16 + wv * 4 + gl;  // pipeline-1 graph

    float arow[8];
    #pragma unroll
    for (int m = 0; m < 8; m++) arow[m] = As[n8 * 8 + m];

    // L1 single-MFMA A-frag (12-slot kappa-packing, see header)
    bf16x8 w1A;
    {
        __bf16 h[3], l[3];
        #pragma unroll
        for (int j = 0; j < 3; j++) {
            float v = W1s[j * 32 + r];
            h[j] = (__bf16)v;
            l[j] = (__bf16)(v - (float)h[j]);
        }
        float bv = b1s[r];
        __bf16 bh = (__bf16)bv;
        __bf16 bl = (__bf16)(bv - (float)bh);
        w1A[0] = q ? l[0] : h[0];
        w1A[1] = q ? l[1] : h[1];
        w1A[2] = q ? l[2] : h[2];
        w1A[3] = q ? l[0] : bh;
        w1A[4] = q ? l[1] : h[0];
        w1A[5] = q ? l[2] : h[1];
        w1A[6] = q ? (__bf16)0.0f : h[2];
        w1A[7] = q ? (__bf16)0.0f : bl;
    }

    // W2 B-frags in pi-order (hi only)
    bf16x8 w2hi[2];
    #pragma unroll
    for (int s = 0; s < 2; s++) {
        #pragma unroll
        for (int j = 0; j < 8; j++) {
            int kk = 8 * s + j;
            int hid = (kk & 3) + 8 * (kk >> 2) + 4 * q;
            w2hi[s][j] = (__bf16)W2s[hid * 32 + r];
        }
    }
    // A32T B-frags in pi-order (hi only)
    bf16x8 a32hi[2];
    #pragma unroll
    for (int s = 0; s < 2; s++) {
        #pragma unroll
        for (int j = 0; j < 8; j++) {
            int kk = 8 * s + j;
            float v = ((kk >> 2) == gl) ? arow[(kk & 3) + 4 * q] : 0.0f;
            a32hi[s][j] = (__bf16)v;
        }
    }
    const float boutv = bout[0];

    // ---- barrier-free compute loop over the 8 pre-staged tiles ----
    #pragma unroll 4
    for (int it = 0; it < TPB; it++) {
        const long long gbase = ((long long)blockIdx.x * TPB + it) * GPT;
        const float* xt = &xs[it * GPT * 24];

        // ---- y = A@x, both pipelines ----
        float y00 = 0.f, y01 = 0.f, y02 = 0.f;
        {
            float xv[24];
            #pragma unroll
            for (int i = 0; i < 6; i++) {
                float4 v = *reinterpret_cast<const float4*>(&xt[g0 * 24 + i * 4]);
                xv[4 * i] = v.x; xv[4 * i + 1] = v.y; xv[4 * i + 2] = v.z; xv[4 * i + 3] = v.w;
            }
            #pragma unroll
            for (int m = 0; m < 8; m++) {
                y00 = fmaf(arow[m], xv[m * 3 + 0], y00);
                y01 = fmaf(arow[m], xv[m * 3 + 1], y01);
                y02 = fmaf(arow[m], xv[m * 3 + 2], y02);
            }
        }
        float y10 = 0.f, y11 = 0.f, y12 = 0.f;
        {
            float xv[24];
            #pragma unroll
            for (int i = 0; i < 6; i++) {
                float4 v = *reinterpret_cast<const float4*>(&xt[g1 * 24 + i * 4]);
                xv[4 * i] = v.x; xv[4 * i + 1] = v.y; xv[4 * i + 2] = v.z; xv[4 * i + 3] = v.w;
            }
            #pragma unroll
            for (int m = 0; m < 8; m++) {
                y10 = fmaf(arow[m], xv[m * 3 + 0], y10);
                y11 = fmaf(arow[m], xv[m * 3 + 1], y11);
                y12 = fmaf(arow[m], xv[m * 3 + 2], y12);
            }
        }

        // ---- yB, 12-slot packing, both pipelines ----
        bf16x8 yB0, yB1;
        {
            __bf16 h0 = (__bf16)y00, h1 = (__bf16)y01, h2 = (__bf16)y02;
            __bf16 l0 = (__bf16)(y00 - (float)h0);
            __bf16 l1 = (__bf16)(y01 - (float)h1);
            __bf16 l2 = (__bf16)(y02 - (float)h2);
            yB0[0] = h0; yB0[1] = h1; yB0[2] = h2;
            yB0[3] = q ? l0 : (__bf16)1.0f;
            yB0[4] = q ? l1 : l0;
            yB0[5] = q ? l2 : l1;
            yB0[6] = q ? (__bf16)0.0f : l2;
            yB0[7] = q ? (__bf16)0.0f : (__bf16)1.0f;
            __bf16 m0 = (__bf16)y10, m1 = (__bf16)y11, m2 = (__bf16)y12;
            __bf16 n0 = (__bf16)(y10 - (float)m0);
            __bf16 n1 = (__bf16)(y11 - (float)m1);
            __bf16 n2 = (__bf16)(y12 - (float)m2);
            yB1[0] = m0; yB1[1] = m1; yB1[2] = m2;
            yB1[3] = q ? n0 : (__bf16)1.0f;
            yB1[4] = q ? n1 : n0;
            yB1[5] = q ? n2 : n1;
            yB1[6] = q ? (__bf16)0.0f : n2;
            yB1[7] = q ? (__bf16)0.0f : (__bf16)1.0f;
        }

        // ---- L1: ONE packed MFMA per pipeline; C explicitly zeroed ----
        f32x16 vacc0, vacc1;
        #pragma unroll
        for (int k = 0; k < 16; k++) { vacc0[k] = 0.0f; vacc1[k] = 0.0f; }
        vacc0 = __builtin_amdgcn_mfma_f32_32x32x16_bf16(w1A, yB0, vacc0, 0, 0, 0);
        vacc1 = __builtin_amdgcn_mfma_f32_32x32x16_bf16(w1A, yB1, vacc1, 0, 0, 0);

        // ---- relu -> h1, hi-only A-frags ----
        bf16x8 phi0[2], phi1[2];
        #pragma unroll
        for (int s = 0; s < 2; s++) {
            #pragma unroll
            for (int j = 0; j < 8; j++) {
                phi0[s][j] = (__bf16)fmaxf(vacc0[8 * s + j], 0.0f);
                phi1[s][j] = (__bf16)fmaxf(vacc1[8 * s + j], 0.0f);
            }
        }

        // ---- GEMM1 MFMAs, interleaved; C explicitly zeroed ----
        #pragma unroll
        for (int k = 0; k < 16; k++) { vacc0[k] = 0.0f; vacc1[k] = 0.0f; }
        vacc0 = __builtin_amdgcn_mfma_f32_32x32x16_bf16(phi0[0], w2hi[0], vacc0, 0, 0, 0);
        vacc1 = __builtin_amdgcn_mfma_f32_32x32x16_bf16(phi1[0], w2hi[0], vacc1, 0, 0, 0);
        vacc0 = __builtin_amdgcn_mfma_f32_32x32x16_bf16(phi0[1], w2hi[1], vacc0, 0, 0, 0);
        vacc1 = __builtin_amdgcn_mfma_f32_32x32x16_bf16(phi1[1], w2hi[1], vacc1, 0, 0, 0);

        // ---- t^T A-frags: hi-only DIRECT conversion ----
        bf16x8 thi0[2], thi1[2];
        #pragma unroll
        for (int s = 0; s < 2; s++) {
            #pragma unroll
            for (int j = 0; j < 8; j++) {
                thi0[s][j] = (__bf16)vacc0[8 * s + j];
                thi1[s][j] = (__bf16)vacc1[8 * s + j];
            }
        }

        // ---- AGG MFMAs, interleaved; C explicitly zeroed (b2 in epilogue) ----
        #pragma unroll
        for (int k = 0; k < 16; k++) { vacc0[k] = 0.0f; vacc1[k] = 0.0f; }
        vacc0 = __builtin_amdgcn_mfma_f32_32x32x16_bf16(thi0[0], a32hi[0], vacc0, 0, 0, 0);
        vacc1 = __builtin_amdgcn_mfma_f32_32x32x16_bf16(thi1[0], a32hi[0], vacc1, 0, 0, 0);
        vacc0 = __builtin_amdgcn_mfma_f32_32x32x16_bf16(thi0[1], a32hi[1], vacc0, 0, 0, 0);
        vacc1 = __builtin_amdgcn_mfma_f32_32x32x16_bf16(thi1[1], a32hi[1], vacc1, 0, 0, 0);

        // ---- epilogue: +b2/relu/wout from LDS (broadcast float4: reg group
        //      gk holds hidden rows 8gk+4q..+3 -> contiguous, 2 addrs/wave) ----
        float ss0 = 0.0f, ss1 = 0.0f;
        #pragma unroll
        for (int gk = 0; gk < 4; gk++) {
            float4 vb = *reinterpret_cast<const float4*>(&b2s[8 * gk + 4 * q]);
            float4 vw = *reinterpret_cast<const float4*>(&Wouts[8 * gk + 4 * q]);
            ss0 = fmaf(fmaxf(vacc0[4 * gk + 0] + vb.x, 0.0f), vw.x, ss0);
            ss0 = fmaf(fmaxf(vacc0[4 * gk + 1] + vb.y, 0.0f), vw.y, ss0);
            ss0 = fmaf(fmaxf(vacc0[4 * gk + 2] + vb.z, 0.0f), vw.z, ss0);
            ss0 = fmaf(fmaxf(vacc0[4 * gk + 3] + vb.w, 0.0f), vw.w, ss0);
            ss1 = fmaf(fmaxf(vacc1[4 * gk + 0] + vb.x, 0.0f), vw.x, ss1);
            ss1 = fmaf(fmaxf(vacc1[4 * gk + 1] + vb.y, 0.0f), vw.y, ss1);
            ss1 = fmaf(fmaxf(vacc1[4 * gk + 2] + vb.z, 0.0f), vw.z, ss1);
            ss1 = fmaf(fmaxf(vacc1[4 * gk + 3] + vb.w, 0.0f), vw.w, ss1);
        }
        ss0 += __shfl_xor(ss0, 32, 64);
        ss1 += __shfl_xor(ss1, 32, 64);
        float o0 = fmaxf(ss0 + boutv, 0.0f);
        float o1 = fmaxf(ss1 + boutv, 0.0f);
        o0 += __shfl_xor(o0, 1, 64);  o1 += __shfl_xor(o1, 1, 64);
        o0 += __shfl_xor(o0, 2, 64);  o1 += __shfl_xor(o1, 2, 64);
        o0 += __shfl_xor(o0, 4, 64);  o1 += __shfl_xor(o1, 4, 64);
        if (q == 0 && n8 == 0) {
            long long gg0 = gbase + g0;
            if (gg0 < (long long)B) out[gg0] = o0 * 0.125f;
            long long gg1 = gbase + g1;
            if (gg1 < (long long)B) out[gg1] = o1 * 0.125f;
        }
    }
}

extern "C" void kernel_launch(void* const* d_in, const int* in_sizes, int n_in,
                              void* d_out, int out_size, void* d_ws, size_t ws_size,
                              hipStream_t stream) {
    const float* x    = (const float*)d_in[0];
    const int*   ei   = (const int*)d_in[1];
    const float* W1   = (const float*)d_in[2];
    const float* b1   = (const float*)d_in[3];
    const float* W2   = (const float*)d_in[4];
    const float* b2   = (const float*)d_in[5];
    const float* Wout = (const float*)d_in[6];
    const float* bout = (const float*)d_in[7];
    float* out = (float*)d_out;
    (void)d_ws; (void)ws_size; (void)out_size; (void)n_in;

    const int B = in_sizes[0] / 24;            // 262144 = 1024 * TPB * GPT exactly
    const int grid = B / (TPB * GPT);          // 1024 blocks, 8 tiles each
    gnn_kernel<<<grid, 256, 0, stream>>>(x, ei, W1, b1, W2, b2, Wout, bout, out, B);
}